// Round 4
// baseline (2252.084 us; speedup 1.0000x reference)
//
#include <hip/hip_runtime.h>
#include <hip/hip_bf16.h>
#include <cstddef>

#define T_LEN 2048
#define H2 256
#define G4 1024   // 4*H2
#define NLBL 32
#define CLS_TAG 0
#define SEP_TAG 31

typedef __attribute__((ext_vector_type(4))) int i32x4;

// ---------------- helpers ----------------

#if defined(__has_builtin)
#if __has_builtin(__builtin_amdgcn_rcpf)
#define HAS_RCPF 1
#endif
#endif

__device__ __forceinline__ float rcpf(float x) {
#ifdef HAS_RCPF
    return __builtin_amdgcn_rcpf(x);
#else
    return 1.0f / x;
#endif
}

__device__ __forceinline__ float sigf(float x) {
    return rcpf(1.0f + __expf(-x));
}

__device__ __forceinline__ float tanhf_(float x) {
    x = fminf(fmaxf(x, -15.0f), 15.0f);
    float e = __expf(2.0f * x);
    return (e - 1.0f) * rcpf(e + 1.0f);
}

// ---------------- kernels ----------------

// 1. gather embeddings
__global__ __launch_bounds__(256) void gather_k(const int* __restrict__ ids,
                                                const float* __restrict__ emb,
                                                float* __restrict__ xbuf) {
    int t = blockIdx.x;
    int row = ids[t];
    xbuf[(size_t)t * 256 + threadIdx.x] = emb[(size_t)row * 256 + threadIdx.x];
}

// 2. quantize w_hh (per-row symmetric int8) AND scatter into MFMA A-fragment
//    layout. One wave per row m (global gate-row 0..1023 per dir).
//    Fragment convention (must match lstm_rec_k's B packing):
//      A-frag(rt,kt): lane l holds rows m=rt*16+(l&15), bytes j=0..15 are
//      k = kt*64 + (l>>4)*16 + j, bytes little-endian within dwords.
__global__ __launch_bounds__(256) void quant_w_k(const float* __restrict__ w_hh_f,
                                                 const float* __restrict__ w_hh_b,
                                                 signed char* __restrict__ wfrag,
                                                 float* __restrict__ srow) {
    int wave = threadIdx.x >> 6, lane = threadIdx.x & 63;   // lane = dword index d
    int rg = blockIdx.x * 4 + wave;              // 0..2047
    int dir = rg >> 10, m = rg & 1023;
    const float* src = (dir ? w_hh_b : w_hh_f) + (size_t)m * H2;
    float4 w4 = ((const float4*)src)[lane];      // k = 4*lane .. 4*lane+3
    float mx = fmaxf(fmaxf(fabsf(w4.x), fabsf(w4.y)), fmaxf(fabsf(w4.z), fabsf(w4.w)));
    #pragma unroll
    for (int off = 32; off; off >>= 1) mx = fmaxf(mx, __shfl_xor(mx, off, 64));
    float s = (mx > 0.0f) ? mx * (1.0f / 127.0f) : 1.0f;
    float inv = rcpf(s);
    int q0 = __float2int_rn(w4.x * inv);
    int q1 = __float2int_rn(w4.y * inv);
    int q2 = __float2int_rn(w4.z * inv);
    int q3 = __float2int_rn(w4.w * inv);
    int packed = (q0 & 255) | ((q1 & 255) << 8) | ((q2 & 255) << 16) | ((q3 & 255) << 24);
    int d = lane;
    int rt = m >> 4, kt = d >> 4, qq = (d >> 2) & 3, j4 = d & 3;
    ((int*)wfrag)[((((size_t)(dir * 64 + rt) * 4 + kt) * 64) + qq * 16 + (m & 15)) * 4 + j4] = packed;
    if (lane == 0) srow[rg] = s;
}

// 3. quantize h0 (per-direction scale), packed bytes k-ascending.
__global__ __launch_bounds__(64) void quant_h0_k(const float* __restrict__ h0,
                                                 int* __restrict__ hq0,
                                                 float* __restrict__ sh0) {
    int dir = blockIdx.x, lane = threadIdx.x;
    float4 h4 = ((const float4*)(h0 + (size_t)dir * H2))[lane];
    float m = fmaxf(fmaxf(fabsf(h4.x), fabsf(h4.y)), fmaxf(fabsf(h4.z), fabsf(h4.w)));
    #pragma unroll
    for (int off = 32; off; off >>= 1) m = fmaxf(m, __shfl_xor(m, off, 64));
    float s = (m > 0.0f) ? m * (1.0f / 127.0f) : 1.0f;
    float inv = rcpf(s);
    int q0 = __float2int_rn(h4.x * inv);
    int q1 = __float2int_rn(h4.y * inv);
    int q2 = __float2int_rn(h4.z * inv);
    int q3 = __float2int_rn(h4.w * inv);
    hq0[dir * 64 + lane] = (q0 & 255) | ((q1 & 255) << 8) | ((q2 & 255) << 16) | ((q3 & 255) << 24);
    if (lane == 0) sh0[dir] = s;
}

// 4. xproj GEMM
__global__ __launch_bounds__(256) void gemm_xproj_k(const float* __restrict__ xbuf,
                                                    const float* __restrict__ w_ih_f,
                                                    const float* __restrict__ w_ih_b,
                                                    const float* __restrict__ b_f,
                                                    const float* __restrict__ b_b,
                                                    float* __restrict__ xproj) {
    __shared__ float As[64][33];
    __shared__ float Bs[64][33];
    int tid = threadIdx.x;
    int t0 = blockIdx.x * 64;
    int n0 = blockIdx.y * 64;
    int tx = tid & 15, ty = tid >> 4;
    float acc[4][4] = {};
    for (int k0 = 0; k0 < 256; k0 += 32) {
        #pragma unroll
        for (int i = 0; i < 8; ++i) {
            int idx = tid + i * 256;
            int r = idx >> 5, kk = idx & 31;
            As[r][kk] = xbuf[(size_t)(t0 + r) * 256 + k0 + kk];
            int nn = n0 + r;
            const float* wsrc = (nn < 1024) ? (w_ih_f + (size_t)nn * 256)
                                            : (w_ih_b + (size_t)(nn - 1024) * 256);
            Bs[r][kk] = wsrc[k0 + kk];
        }
        __syncthreads();
        #pragma unroll
        for (int kk = 0; kk < 32; ++kk) {
            float a[4], b[4];
            #pragma unroll
            for (int i = 0; i < 4; ++i) a[i] = As[ty * 4 + i][kk];
            #pragma unroll
            for (int j = 0; j < 4; ++j) b[j] = Bs[tx * 4 + j][kk];
            #pragma unroll
            for (int i = 0; i < 4; ++i)
                #pragma unroll
                for (int j = 0; j < 4; ++j) acc[i][j] += a[i] * b[j];
        }
        __syncthreads();
    }
    #pragma unroll
    for (int j = 0; j < 4; ++j) {
        int nn = n0 + tx * 4 + j;
        int dir = nn >> 10, nl = nn & 1023;
        float bias = dir ? b_b[nl] : b_f[nl];
        #pragma unroll
        for (int i = 0; i < 4; ++i) {
            int t = t0 + ty * 4 + i;
            xproj[((size_t)dir * T_LEN + t) * G4 + nl] = acc[i][j] + bias;
        }
    }
}

// 5. LSTM recurrence v4 (MFMA). grid = 2, block = 512 (8 waves).
//    Wave w holds A-fragments for row-tiles w*8..w*8+7 (128 regs; AGPR-OK
//    since MFMA reads A from AGPR natively). h replicated across B columns:
//    every quad broadcast-reads the same 16 bytes of hq -> all D columns
//    equal W*h. Lanes (lane&15)==0 publish z (int32) to LDS; threads <256
//    do the gate math.
__global__ __launch_bounds__(512, 2) void lstm_rec_k(const signed char* __restrict__ wfrag,
                                                     const float* __restrict__ srow,
                                                     const float* __restrict__ xproj,
                                                     const int* __restrict__ hq0,
                                                     const float* __restrict__ sh0v,
                                                     const float* __restrict__ c0,
                                                     float* __restrict__ hs) {
    const int dir = blockIdx.x;
    const int tid = threadIdx.x;        // 0..511
    const int wv  = tid >> 6;           // wave 0..7
    const int lane = tid & 63;
    const int q = lane >> 4;            // quad
    __shared__ i32x4 hq[2][16];         // ping-pong packed int8 hidden state
    __shared__ int   zbuf[G4];          // raw int32 dots, indexed by gate-row

    // A fragments: 8 row-tiles x 4 k-tiles x 16B
    i32x4 A[8][4];
    #pragma unroll
    for (int r = 0; r < 8; ++r) {
        int rt = wv * 8 + r;
        #pragma unroll
        for (int kt = 0; kt < 4; ++kt)
            A[r][kt] = *(const i32x4*)(wfrag +
                (((size_t)((dir * 64 + rt) * 4 + kt)) * 64 + lane) * 16);
    }

    float sr[4], c = 0.0f, zx[4];
    const float* xp = xproj + (size_t)dir * T_LEN * G4;
    if (tid < H2) {
        #pragma unroll
        for (int g = 0; g < 4; ++g) sr[g] = srow[dir * G4 + g * H2 + tid];
        c = c0[dir * H2 + tid];
    }
    float sh = sh0v[dir];
    if (tid < 16) hq[0][tid] = ((const i32x4*)hq0)[dir * 16 + tid];

    int t = dir ? (T_LEN - 1) : 0;
    const int stp = dir ? -1 : 1;
    if (tid < H2) {
        #pragma unroll
        for (int g = 0; g < 4; ++g) zx[g] = xp[(size_t)t * G4 + g * H2 + tid];
    }
    __syncthreads();

    for (int s = 0; s < T_LEN; ++s) {
        const int buf = s & 1;
        const char* hb = (const char*)&hq[buf][0];
        i32x4 B0 = *(const i32x4*)(hb + 0 * 64 + q * 16);   // broadcast per quad
        i32x4 B1 = *(const i32x4*)(hb + 1 * 64 + q * 16);
        i32x4 B2 = *(const i32x4*)(hb + 2 * 64 + q * 16);
        i32x4 B3 = *(const i32x4*)(hb + 3 * 64 + q * 16);
        #pragma unroll
        for (int r = 0; r < 8; ++r) {
            i32x4 acc = {0, 0, 0, 0};
            acc = __builtin_amdgcn_mfma_i32_16x16x64_i8(A[r][0], B0, acc, 0, 0, 0);
            acc = __builtin_amdgcn_mfma_i32_16x16x64_i8(A[r][1], B1, acc, 0, 0, 0);
            acc = __builtin_amdgcn_mfma_i32_16x16x64_i8(A[r][2], B2, acc, 0, 0, 0);
            acc = __builtin_amdgcn_mfma_i32_16x16x64_i8(A[r][3], B3, acc, 0, 0, 0);
            if ((lane & 15) == 0) {                    // col 0 (all cols equal)
                int rt = wv * 8 + r;                   // rows rt*16 + q*4 + reg
                *(i32x4*)&zbuf[rt * 16 + q * 4] = acc;
            }
        }
        __syncthreads();
        int tn = (s == T_LEN - 1) ? t : t + stp;
        if (tid < H2) {
            float znx[4];
            #pragma unroll
            for (int g = 0; g < 4; ++g) znx[g] = xp[(size_t)tn * G4 + g * H2 + tid];
            float z[4];
            #pragma unroll
            for (int g = 0; g < 4; ++g)
                z[g] = (float)zbuf[g * H2 + tid] * (sr[g] * sh) + zx[g];
            float ig = sigf(z[0]), fg = sigf(z[1]), gg = tanhf_(z[2]), og = sigf(z[3]);
            c = fg * c + ig * gg;
            float h = og * tanhf_(c);
            hs[(size_t)t * 512 + dir * H2 + tid] = h;
            int qv = __float2int_rn(fminf(fmaxf(h * 127.0f, -127.0f), 127.0f));
            ((signed char*)&hq[1 - buf][0])[tid] = (signed char)qv;
            #pragma unroll
            for (int g = 0; g < 4; ++g) zx[g] = znx[g];
        }
        sh = 1.0f / 127.0f;
        t = tn;
        __syncthreads();                               // publish hq[1-buf]
    }
}

// 6. logits
__global__ __launch_bounds__(128) void logits_k(const float* __restrict__ hs,
                                                const float* __restrict__ w_lin,
                                                const float* __restrict__ b_lin,
                                                float* __restrict__ logits) {
    __shared__ float wldT[512][17];
    __shared__ float hld[8][512];
    int tid = threadIdx.x;
    int t0 = blockIdx.x * 8;
    int n0 = blockIdx.y * 16;
    for (int i = tid; i < 16 * 512; i += 128) {
        int j = i >> 9, k = i & 511;
        wldT[k][j] = w_lin[(size_t)(n0 + j) * 512 + k];
    }
    for (int i = tid; i < 8 * 512; i += 128) {
        int tq = i >> 9, k = i & 511;
        hld[tq][k] = hs[(size_t)(t0 + tq) * 512 + k];
    }
    __syncthreads();
    int j = tid & 15, tq = tid >> 4;
    float acc = b_lin[n0 + j];
    #pragma unroll 8
    for (int k = 0; k < 512; ++k) acc += hld[tq][k] * wldT[k][j];
    logits[(size_t)(t0 + tq) * NLBL + n0 + j] = acc;
}

// 7. gold path score
__global__ __launch_bounds__(256) void gold_k(const float* __restrict__ trans,
                                              const int* __restrict__ target,
                                              const float* __restrict__ logits,
                                              float* __restrict__ gold) {
    __shared__ float red[256];
    int tid = threadIdx.x;
    float s = 0.0f;
    for (int t = tid; t < T_LEN; t += 256) {
        int cur = target[t];
        int prev = (t == 0) ? CLS_TAG : target[t - 1];
        s += trans[cur * NLBL + prev] + logits[(size_t)t * NLBL + cur];
    }
    if (tid == 0) s += trans[SEP_TAG * NLBL + target[T_LEN - 1]];
    red[tid] = s;
    __syncthreads();
    for (int st = 128; st; st >>= 1) {
        if (tid < st) red[tid] += red[tid + st];
        __syncthreads();
    }
    if (tid == 0) gold[0] = red[0];
}

// 8a. CRF tree level 0
__global__ __launch_bounds__(1024) void crf_chain0_k(const float* __restrict__ logits,
                                                     const float* __restrict__ trans,
                                                     float* __restrict__ mats) {
    const int tid = threadIdx.x;
    const int n = tid >> 5, p = tid & 31;
    __shared__ float Rl[2][NLBL][NLBL + 1];
    __shared__ float tl[NLBL][NLBL + 1];
    const int t0 = blockIdx.x * 8;
    float e[8];
    #pragma unroll
    for (int s = 0; s < 8; ++s) e[s] = logits[(size_t)(t0 + s) * NLBL + n];
    float myt = trans[n * NLBL + p];
    tl[n][p] = myt;
    __syncthreads();
    float tr[NLBL];
    #pragma unroll
    for (int k = 0; k < NLBL; ++k) tr[k] = tl[n][k];
    Rl[0][n][p] = myt + e[0];
    __syncthreads();
    float rn = 0.0f;
    for (int s = 1; s < 8; ++s) {
        const int cur = (s - 1) & 1, nxt = s & 1;
        float v[NLBL];
        #pragma unroll
        for (int k = 0; k < NLBL; ++k) v[k] = tr[k] + Rl[cur][k][p];
        float m = v[0];
        #pragma unroll
        for (int k = 1; k < NLBL; ++k) m = fmaxf(m, v[k]);
        float sum = 0.0f;
        #pragma unroll
        for (int k = 0; k < NLBL; ++k) sum += __expf(v[k] - m);
        rn = e[s] + m + __logf(sum);
        Rl[nxt][n][p] = rn;
        __syncthreads();
    }
    mats[(size_t)blockIdx.x * 1024 + tid] = rn;
}

// 8b. CRF tree level N
__global__ __launch_bounds__(1024) void crf_chainN_k(const float* __restrict__ min_,
                                                     float* __restrict__ mout,
                                                     int chunk) {
    const int tid = threadIdx.x;
    const int n = tid >> 5, p = tid & 31;
    __shared__ float Rl[2][NLBL][NLBL + 1];
    __shared__ float Al[2][NLBL][NLBL + 1];
    const size_t base = (size_t)blockIdx.x * chunk;
    float rn = min_[base * 1024 + tid];
    Rl[0][n][p] = rn;
    float anext = min_[(base + 1) * 1024 + tid];
    __syncthreads();
    for (int s = 1; s < chunk; ++s) {
        const int cur = (s - 1) & 1, nxt = s & 1;
        Al[nxt][n][p] = anext;
        if (s + 1 < chunk) anext = min_[(base + s + 1) * 1024 + tid];
        __syncthreads();
        float v[NLBL];
        #pragma unroll
        for (int k = 0; k < NLBL; ++k) v[k] = Al[nxt][n][k] + Rl[cur][k][p];
        float m = v[0];
        #pragma unroll
        for (int k = 1; k < NLBL; ++k) m = fmaxf(m, v[k]);
        float sum = 0.0f;
        #pragma unroll
        for (int k = 0; k < NLBL; ++k) sum += __expf(v[k] - m);
        rn = m + __logf(sum);
        Rl[nxt][n][p] = rn;
        __syncthreads();
    }
    mout[(size_t)blockIdx.x * 1024 + tid] = rn;
}

// 8c. CRF finish
__global__ __launch_bounds__(1024) void crf_finish_k(const float* __restrict__ min_,
                                                     const float* __restrict__ trans,
                                                     const float* __restrict__ gold,
                                                     float* __restrict__ out,
                                                     int chunk) {
    const int tid = threadIdx.x;
    const int n = tid >> 5, p = tid & 31;
    __shared__ float Rl[2][NLBL][NLBL + 1];
    __shared__ float Al[2][NLBL][NLBL + 1];
    __shared__ float af[NLBL];
    float rn = min_[tid];
    Rl[0][n][p] = rn;
    float anext = min_[1024 + tid];
    __syncthreads();
    for (int s = 1; s < chunk; ++s) {
        const int cur = (s - 1) & 1, nxt = s & 1;
        Al[nxt][n][p] = anext;
        if (s + 1 < chunk) anext = min_[(size_t)(s + 1) * 1024 + tid];
        __syncthreads();
        float v[NLBL];
        #pragma unroll
        for (int k = 0; k < NLBL; ++k) v[k] = Al[nxt][n][k] + Rl[cur][k][p];
        float m = v[0];
        #pragma unroll
        for (int k = 1; k < NLBL; ++k) m = fmaxf(m, v[k]);
        float sum = 0.0f;
        #pragma unroll
        for (int k = 0; k < NLBL; ++k) sum += __expf(v[k] - m);
        rn = m + __logf(sum);
        Rl[nxt][n][p] = rn;
        __syncthreads();
    }
    float val = rn + ((p == CLS_TAG) ? 0.0f : -10000.0f);
    float m = val;
    #pragma unroll
    for (int off = 16; off; off >>= 1) m = fmaxf(m, __shfl_xor(m, off, 32));
    float esum = __expf(val - m);
    #pragma unroll
    for (int off = 16; off; off >>= 1) esum += __shfl_xor(esum, off, 32);
    if (p == 0) af[n] = m + __logf(esum);
    __syncthreads();
    if (tid < NLBL) {
        float f = af[tid] + trans[SEP_TAG * NLBL + tid];
        float mm = f;
        #pragma unroll
        for (int off = 16; off; off >>= 1) mm = fmaxf(mm, __shfl_xor(mm, off, 32));
        float es = __expf(f - mm);
        #pragma unroll
        for (int off = 16; off; off >>= 1) es += __shfl_xor(es, off, 32);
        if (tid == 0) out[0] = mm + __logf(es) - gold[0];
    }
}

// ---------------- launch ----------------

extern "C" void kernel_launch(void* const* d_in, const int* in_sizes, int n_in,
                              void* d_out, int out_size, void* d_ws, size_t ws_size,
                              hipStream_t stream) {
    const int*   ids     = (const int*)d_in[0];
    const int*   target  = (const int*)d_in[2];
    const float* emb     = (const float*)d_in[3];
    const float* w_ih_f  = (const float*)d_in[4];
    const float* w_hh_f  = (const float*)d_in[5];
    const float* b_f     = (const float*)d_in[6];
    const float* w_ih_b  = (const float*)d_in[7];
    const float* w_hh_b  = (const float*)d_in[8];
    const float* b_b     = (const float*)d_in[9];
    const float* w_lin   = (const float*)d_in[10];
    const float* b_lin   = (const float*)d_in[11];
    const float* trans   = (const float*)d_in[12];
    const float* h0      = (const float*)d_in[13];
    const float* c0      = (const float*)d_in[14];
    float* out = (float*)d_out;

    char* ws = (char*)d_ws;
    size_t off = 0;
    float* xbuf   = (float*)(ws + off); off += (size_t)T_LEN * 256 * 4;       // 2 MB
    float* xproj  = (float*)(ws + off); off += (size_t)2 * T_LEN * G4 * 4;    // 16 MB
    float* hs     = (float*)(ws + off); off += (size_t)T_LEN * 512 * 4;       // 4 MB
    float* logits = (float*)(ws + off); off += (size_t)T_LEN * NLBL * 4;      // 256 KB
    float* srow   = (float*)(ws + off); off += (size_t)2 * G4 * 4;            // 8 KB
    float* sh0v   = (float*)(ws + off); off += 16;
    float* gold   = (float*)(ws + off); off += 16;
    int*   hq0    = (int*)(ws + off);   off += (size_t)2 * 64 * 4;
    signed char* wfrag = (signed char*)(ws + off); off += (size_t)2 * G4 * H2; // 512 KB
    float* mats1 = xbuf;                 // alias xbuf (dead after gemm_xproj)
    float* mats2 = xbuf + 256 * 1024;

    gather_k<<<T_LEN, 256, 0, stream>>>(ids, emb, xbuf);
    quant_w_k<<<512, 256, 0, stream>>>(w_hh_f, w_hh_b, wfrag, srow);
    quant_h0_k<<<2, 64, 0, stream>>>(h0, hq0, sh0v);
    gemm_xproj_k<<<dim3(32, 32), 256, 0, stream>>>(xbuf, w_ih_f, w_ih_b, b_f, b_b, xproj);
    lstm_rec_k<<<2, 512, 0, stream>>>(wfrag, srow, xproj, hq0, sh0v, c0, hs);
    logits_k<<<dim3(256, 2), 128, 0, stream>>>(hs, w_lin, b_lin, logits);
    gold_k<<<1, 256, 0, stream>>>(trans, target, logits, gold);
    crf_chain0_k<<<256, 1024, 0, stream>>>(logits, trans, mats1);
    crf_chainN_k<<<16, 1024, 0, stream>>>(mats1, mats2, 16);
    crf_finish_k<<<1, 1024, 0, stream>>>(mats2, trans, gold, out, 16);
}

// Round 5
// 2223.655 us; speedup vs baseline: 1.0128x; 1.0128x over previous
//
#include <hip/hip_runtime.h>
#include <hip/hip_bf16.h>
#include <cstddef>

#define T_LEN 2048
#define H2 256
#define G4 1024   // 4*H2
#define NLBL 32
#define CLS_TAG 0
#define SEP_TAG 31

// ---------------- helpers ----------------

#if defined(__has_builtin)
#if __has_builtin(__builtin_amdgcn_sdot4)
#define HAS_SDOT4 1
#endif
#if __has_builtin(__builtin_amdgcn_rcpf)
#define HAS_RCPF 1
#endif
#endif

// int8 dot4: inline asm with "v" constraints forces ArchVGPR operands so the
// allocator keeps the 128 weight dwords in real VGPRs (v1/v3 showed the
// builtin path lets them demote to AGPRs -> accvgpr moves double VALU issue).
__device__ __forceinline__ void sdot(int& acc, int a, int b) {
#if defined(__gfx950__) || defined(__gfx942__) || defined(__gfx90a__)
    asm("v_dot4_i32_i8 %0, %1, %2, %0" : "+v"(acc) : "v"(a), "v"(b));
#elif defined(HAS_SDOT4)
    acc = __builtin_amdgcn_sdot4(a, b, acc, false);
#else
    acc += (int)((signed char)(a & 0xff))         * (int)((signed char)(b & 0xff));
    acc += (int)((signed char)((a >> 8) & 0xff))  * (int)((signed char)((b >> 8) & 0xff));
    acc += (int)((signed char)((a >> 16) & 0xff)) * (int)((signed char)((b >> 16) & 0xff));
    acc += (int)((signed char)(a >> 24))          * (int)((signed char)(b >> 24));
#endif
}

__device__ __forceinline__ float rcpf(float x) {
#ifdef HAS_RCPF
    return __builtin_amdgcn_rcpf(x);
#else
    return 1.0f / x;
#endif
}

__device__ __forceinline__ float sigf(float x) {
    return rcpf(1.0f + __expf(-x));
}

__device__ __forceinline__ float tanhf_(float x) {
    x = fminf(fmaxf(x, -15.0f), 15.0f);
    float e = __expf(2.0f * x);
    return (e - 1.0f) * rcpf(e + 1.0f);
}

// ---------------- kernels ----------------

// 1. gather embeddings
__global__ __launch_bounds__(256) void gather_k(const int* __restrict__ ids,
                                                const float* __restrict__ emb,
                                                float* __restrict__ xbuf) {
    int t = blockIdx.x;
    int row = ids[t];
    xbuf[(size_t)t * 256 + threadIdx.x] = emb[(size_t)row * 256 + threadIdx.x];
}

// 2. quantize w_hh (per-row symmetric int8) into PERMUTED row order:
//    original gate-row n (i/f/g/o blocks of 256) -> prow = (n&255)*4 + (n>>8)
//    so rows 4u..4u+3 are gates i,f,g,o of unit u. One wave per row.
__global__ __launch_bounds__(256) void quant_w_k(const float* __restrict__ w_hh_f,
                                                 const float* __restrict__ w_hh_b,
                                                 signed char* __restrict__ wq,
                                                 float* __restrict__ srowP) {
    int wave = threadIdx.x >> 6, lane = threadIdx.x & 63;
    int rg = blockIdx.x * 4 + wave;              // 0..2047
    int dir = rg >> 10, m = rg & 1023;
    int prow = (m & 255) * 4 + (m >> 8);
    const float* src = (dir ? w_hh_b : w_hh_f) + (size_t)m * H2;
    float4 w4 = ((const float4*)src)[lane];
    float mx = fmaxf(fmaxf(fabsf(w4.x), fabsf(w4.y)), fmaxf(fabsf(w4.z), fabsf(w4.w)));
    #pragma unroll
    for (int off = 32; off; off >>= 1) mx = fmaxf(mx, __shfl_xor(mx, off, 64));
    float s = (mx > 0.0f) ? mx * (1.0f / 127.0f) : 1.0f;
    float inv = rcpf(s);
    int q0 = __float2int_rn(w4.x * inv);
    int q1 = __float2int_rn(w4.y * inv);
    int q2 = __float2int_rn(w4.z * inv);
    int q3 = __float2int_rn(w4.w * inv);
    int packed = (q0 & 255) | ((q1 & 255) << 8) | ((q2 & 255) << 16) | ((q3 & 255) << 24);
    ((int*)wq)[((size_t)(dir * G4 + prow)) * 64 + lane] = packed;
    if (lane == 0) srowP[dir * G4 + prow] = s;
}

// 3. quantize h0 (per-direction scale), bytes unit-ascending.
__global__ __launch_bounds__(64) void quant_h0_k(const float* __restrict__ h0,
                                                 int* __restrict__ hq0,
                                                 float* __restrict__ sh0) {
    int dir = blockIdx.x, lane = threadIdx.x;
    float4 h4 = ((const float4*)(h0 + (size_t)dir * H2))[lane];
    float m = fmaxf(fmaxf(fabsf(h4.x), fabsf(h4.y)), fmaxf(fabsf(h4.z), fabsf(h4.w)));
    #pragma unroll
    for (int off = 32; off; off >>= 1) m = fmaxf(m, __shfl_xor(m, off, 64));
    float s = (m > 0.0f) ? m * (1.0f / 127.0f) : 1.0f;
    float inv = rcpf(s);
    int q0 = __float2int_rn(h4.x * inv);
    int q1 = __float2int_rn(h4.y * inv);
    int q2 = __float2int_rn(h4.z * inv);
    int q3 = __float2int_rn(h4.w * inv);
    hq0[dir * 64 + lane] = (q0 & 255) | ((q1 & 255) << 8) | ((q2 & 255) << 16) | ((q3 & 255) << 24);
    if (lane == 0) sh0[dir] = s;
}

// 4. xproj GEMM -> PERMUTED output: xprojP[dir][t][u*4+g] = x[t].w_ih[g*256+u] + b
__global__ __launch_bounds__(256) void gemm_xproj_k(const float* __restrict__ xbuf,
                                                    const float* __restrict__ w_ih_f,
                                                    const float* __restrict__ w_ih_b,
                                                    const float* __restrict__ b_f,
                                                    const float* __restrict__ b_b,
                                                    float* __restrict__ xprojP) {
    __shared__ float As[64][33];
    __shared__ float Bs[64][33];
    int tid = threadIdx.x;
    int t0 = blockIdx.x * 64;
    int n0 = blockIdx.y * 64;
    int tx = tid & 15, ty = tid >> 4;
    float acc[4][4] = {};
    for (int k0 = 0; k0 < 256; k0 += 32) {
        #pragma unroll
        for (int i = 0; i < 8; ++i) {
            int idx = tid + i * 256;
            int r = idx >> 5, kk = idx & 31;
            As[r][kk] = xbuf[(size_t)(t0 + r) * 256 + k0 + kk];
            int nn = n0 + r;
            const float* wsrc = (nn < 1024) ? (w_ih_f + (size_t)nn * 256)
                                            : (w_ih_b + (size_t)(nn - 1024) * 256);
            Bs[r][kk] = wsrc[k0 + kk];
        }
        __syncthreads();
        #pragma unroll
        for (int kk = 0; kk < 32; ++kk) {
            float a[4], b[4];
            #pragma unroll
            for (int i = 0; i < 4; ++i) a[i] = As[ty * 4 + i][kk];
            #pragma unroll
            for (int j = 0; j < 4; ++j) b[j] = Bs[tx * 4 + j][kk];
            #pragma unroll
            for (int i = 0; i < 4; ++i)
                #pragma unroll
                for (int j = 0; j < 4; ++j) acc[i][j] += a[i] * b[j];
        }
        __syncthreads();
    }
    #pragma unroll
    for (int j = 0; j < 4; ++j) {
        int nn = n0 + tx * 4 + j;
        int dir = nn >> 10, nl = nn & 1023;
        float bias = dir ? b_b[nl] : b_f[nl];
        int pidx = (nl & 255) * 4 + (nl >> 8);
        #pragma unroll
        for (int i = 0; i < 4; ++i) {
            int t = t0 + ty * 4 + i;
            xprojP[((size_t)dir * T_LEN + t) * G4 + pidx] = acc[i][j] + bias;
        }
    }
}

// 5. LSTM recurrence v5 (sdot, pair-threads). grid = 2, block = 512.
//    Thread x owns permuted rows 2x,2x+1 = 2 gates of unit u=x>>1; lane
//    neighbor x^1 owns the other 2 gates -> shfl exchange, no zbuf,
//    ONE barrier per step, all 8 waves uniform.
__global__ __launch_bounds__(512, 2) void lstm_rec_k(const signed char* __restrict__ wq,
                                                     const float* __restrict__ srowP,
                                                     const float* __restrict__ xprojP,
                                                     const int* __restrict__ hq0,
                                                     const float* __restrict__ sh0v,
                                                     const float* __restrict__ c0,
                                                     float* __restrict__ hs) {
    const int dir = blockIdx.x;
    const int x = threadIdx.x;            // 0..511
    const int u = x >> 1;                 // unit
    const bool lo = (x & 1) == 0;         // even: rows = gates i,f ; odd: g,o
    __shared__ int hqs[2][64];            // packed int8 h, ping-pong

    // weights: permuted rows 2x, 2x+1 -> 128 dwords in VGPRs (asm-pinned)
    int w0[64], w1[64];
    {
        const int4* wr4 = (const int4*)((const int*)wq + ((size_t)(dir * G4 + 2 * x)) * 64);
        #pragma unroll
        for (int k = 0; k < 16; ++k) {
            int4 a = wr4[k];
            w0[4 * k] = a.x; w0[4 * k + 1] = a.y; w0[4 * k + 2] = a.z; w0[4 * k + 3] = a.w;
        }
        #pragma unroll
        for (int k = 0; k < 16; ++k) {
            int4 a = wr4[16 + k];
            w1[4 * k] = a.x; w1[4 * k + 1] = a.y; w1[4 * k + 2] = a.z; w1[4 * k + 3] = a.w;
        }
    }
    float2 sr = ((const float2*)(srowP + dir * G4))[x];
    float sh = sh0v[dir];
    float c = c0[dir * H2 + u];           // replicated per pair
    const float2* xp2 = (const float2*)(xprojP + (size_t)dir * T_LEN * G4);
    if (x < 64) hqs[0][x] = hq0[dir * 64 + x];

    int t = dir ? (T_LEN - 1) : 0;
    const int stp = dir ? -1 : 1;
    float2 zx = xp2[(size_t)t * 512 + x];
    __syncthreads();

    for (int s = 0; s < T_LEN; ++s) {
        const int buf = s & 1;
        int tn = (s == T_LEN - 1) ? t : t + stp;
        float2 zxn = xp2[(size_t)tn * 512 + x];          // prefetch next step

        int a0 = 0, a1 = 0;
        const int4* hb = (const int4*)hqs[buf];
        #pragma unroll
        for (int k = 0; k < 16; ++k) {
            int4 hv = hb[k];                              // broadcast read
            sdot(a0, w0[4 * k],     hv.x);
            sdot(a1, w1[4 * k],     hv.x);
            sdot(a0, w0[4 * k + 1], hv.y);
            sdot(a1, w1[4 * k + 1], hv.y);
            sdot(a0, w0[4 * k + 2], hv.z);
            sdot(a1, w1[4 * k + 2], hv.z);
            sdot(a0, w0[4 * k + 3], hv.w);
            sdot(a1, w1[4 * k + 3], hv.w);
        }
        float z0 = zx.x + sr.x * sh * (float)a0;
        float z1 = zx.y + sr.y * sh * (float)a1;
        float zp0 = __shfl_xor(z0, 1, 64);                // partner's gates
        float zp1 = __shfl_xor(z1, 1, 64);
        float zi = lo ? z0 : zp0;
        float zf = lo ? z1 : zp1;
        float zg = lo ? zp0 : z0;
        float zo = lo ? zp1 : z1;
        float ig = sigf(zi), fg = sigf(zf), gg = tanhf_(zg), og = sigf(zo);
        c = fg * c + ig * gg;
        float h = og * tanhf_(c);
        int qv = __float2int_rn(fminf(fmaxf(h * 127.0f, -127.0f), 127.0f));
        if (lo) {
            hs[(size_t)t * 512 + dir * H2 + u] = h;
            ((signed char*)hqs[1 - buf])[u] = (signed char)qv;
        }
        sh = 1.0f / 127.0f;
        zx = zxn;
        t = tn;
        __syncthreads();                                  // publish hqs[1-buf]
    }
}

// 6. logits
__global__ __launch_bounds__(128) void logits_k(const float* __restrict__ hs,
                                                const float* __restrict__ w_lin,
                                                const float* __restrict__ b_lin,
                                                float* __restrict__ logits) {
    __shared__ float wldT[512][17];
    __shared__ float hld[8][512];
    int tid = threadIdx.x;
    int t0 = blockIdx.x * 8;
    int n0 = blockIdx.y * 16;
    for (int i = tid; i < 16 * 512; i += 128) {
        int j = i >> 9, k = i & 511;
        wldT[k][j] = w_lin[(size_t)(n0 + j) * 512 + k];
    }
    for (int i = tid; i < 8 * 512; i += 128) {
        int tq = i >> 9, k = i & 511;
        hld[tq][k] = hs[(size_t)(t0 + tq) * 512 + k];
    }
    __syncthreads();
    int j = tid & 15, tq = tid >> 4;
    float acc = b_lin[n0 + j];
    #pragma unroll 8
    for (int k = 0; k < 512; ++k) acc += hld[tq][k] * wldT[k][j];
    logits[(size_t)(t0 + tq) * NLBL + n0 + j] = acc;
}

// 7. gold path score
__global__ __launch_bounds__(256) void gold_k(const float* __restrict__ trans,
                                              const int* __restrict__ target,
                                              const float* __restrict__ logits,
                                              float* __restrict__ gold) {
    __shared__ float red[256];
    int tid = threadIdx.x;
    float s = 0.0f;
    for (int t = tid; t < T_LEN; t += 256) {
        int cur = target[t];
        int prev = (t == 0) ? CLS_TAG : target[t - 1];
        s += trans[cur * NLBL + prev] + logits[(size_t)t * NLBL + cur];
    }
    if (tid == 0) s += trans[SEP_TAG * NLBL + target[T_LEN - 1]];
    red[tid] = s;
    __syncthreads();
    for (int st = 128; st; st >>= 1) {
        if (tid < st) red[tid] += red[tid + st];
        __syncthreads();
    }
    if (tid == 0) gold[0] = red[0];
}

// 8a. CRF tree level 0
__global__ __launch_bounds__(1024) void crf_chain0_k(const float* __restrict__ logits,
                                                     const float* __restrict__ trans,
                                                     float* __restrict__ mats) {
    const int tid = threadIdx.x;
    const int n = tid >> 5, p = tid & 31;
    __shared__ float Rl[2][NLBL][NLBL + 1];
    __shared__ float tl[NLBL][NLBL + 1];
    const int t0 = blockIdx.x * 8;
    float e[8];
    #pragma unroll
    for (int s = 0; s < 8; ++s) e[s] = logits[(size_t)(t0 + s) * NLBL + n];
    float myt = trans[n * NLBL + p];
    tl[n][p] = myt;
    __syncthreads();
    float tr[NLBL];
    #pragma unroll
    for (int k = 0; k < NLBL; ++k) tr[k] = tl[n][k];
    Rl[0][n][p] = myt + e[0];
    __syncthreads();
    float rn = 0.0f;
    for (int s = 1; s < 8; ++s) {
        const int cur = (s - 1) & 1, nxt = s & 1;
        float v[NLBL];
        #pragma unroll
        for (int k = 0; k < NLBL; ++k) v[k] = tr[k] + Rl[cur][k][p];
        float m = v[0];
        #pragma unroll
        for (int k = 1; k < NLBL; ++k) m = fmaxf(m, v[k]);
        float sum = 0.0f;
        #pragma unroll
        for (int k = 0; k < NLBL; ++k) sum += __expf(v[k] - m);
        rn = e[s] + m + __logf(sum);
        Rl[nxt][n][p] = rn;
        __syncthreads();
    }
    mats[(size_t)blockIdx.x * 1024 + tid] = rn;
}

// 8b. CRF tree level N
__global__ __launch_bounds__(1024) void crf_chainN_k(const float* __restrict__ min_,
                                                     float* __restrict__ mout,
                                                     int chunk) {
    const int tid = threadIdx.x;
    const int n = tid >> 5, p = tid & 31;
    __shared__ float Rl[2][NLBL][NLBL + 1];
    __shared__ float Al[2][NLBL][NLBL + 1];
    const size_t base = (size_t)blockIdx.x * chunk;
    float rn = min_[base * 1024 + tid];
    Rl[0][n][p] = rn;
    float anext = min_[(base + 1) * 1024 + tid];
    __syncthreads();
    for (int s = 1; s < chunk; ++s) {
        const int cur = (s - 1) & 1, nxt = s & 1;
        Al[nxt][n][p] = anext;
        if (s + 1 < chunk) anext = min_[(base + s + 1) * 1024 + tid];
        __syncthreads();
        float v[NLBL];
        #pragma unroll
        for (int k = 0; k < NLBL; ++k) v[k] = Al[nxt][n][k] + Rl[cur][k][p];
        float m = v[0];
        #pragma unroll
        for (int k = 1; k < NLBL; ++k) m = fmaxf(m, v[k]);
        float sum = 0.0f;
        #pragma unroll
        for (int k = 0; k < NLBL; ++k) sum += __expf(v[k] - m);
        rn = m + __logf(sum);
        Rl[nxt][n][p] = rn;
        __syncthreads();
    }
    mout[(size_t)blockIdx.x * 1024 + tid] = rn;
}

// 8c. CRF finish
__global__ __launch_bounds__(1024) void crf_finish_k(const float* __restrict__ min_,
                                                     const float* __restrict__ trans,
                                                     const float* __restrict__ gold,
                                                     float* __restrict__ out,
                                                     int chunk) {
    const int tid = threadIdx.x;
    const int n = tid >> 5, p = tid & 31;
    __shared__ float Rl[2][NLBL][NLBL + 1];
    __shared__ float Al[2][NLBL][NLBL + 1];
    __shared__ float af[NLBL];
    float rn = min_[tid];
    Rl[0][n][p] = rn;
    float anext = min_[1024 + tid];
    __syncthreads();
    for (int s = 1; s < chunk; ++s) {
        const int cur = (s - 1) & 1, nxt = s & 1;
        Al[nxt][n][p] = anext;
        if (s + 1 < chunk) anext = min_[(size_t)(s + 1) * 1024 + tid];
        __syncthreads();
        float v[NLBL];
        #pragma unroll
        for (int k = 0; k < NLBL; ++k) v[k] = Al[nxt][n][k] + Rl[cur][k][p];
        float m = v[0];
        #pragma unroll
        for (int k = 1; k < NLBL; ++k) m = fmaxf(m, v[k]);
        float sum = 0.0f;
        #pragma unroll
        for (int k = 0; k < NLBL; ++k) sum += __expf(v[k] - m);
        rn = m + __logf(sum);
        Rl[nxt][n][p] = rn;
        __syncthreads();
    }
    float val = rn + ((p == CLS_TAG) ? 0.0f : -10000.0f);
    float m = val;
    #pragma unroll
    for (int off = 16; off; off >>= 1) m = fmaxf(m, __shfl_xor(m, off, 32));
    float esum = __expf(val - m);
    #pragma unroll
    for (int off = 16; off; off >>= 1) esum += __shfl_xor(esum, off, 32);
    if (p == 0) af[n] = m + __logf(esum);
    __syncthreads();
    if (tid < NLBL) {
        float f = af[tid] + trans[SEP_TAG * NLBL + tid];
        float mm = f;
        #pragma unroll
        for (int off = 16; off; off >>= 1) mm = fmaxf(mm, __shfl_xor(mm, off, 32));
        float es = __expf(f - mm);
        #pragma unroll
        for (int off = 16; off; off >>= 1) es += __shfl_xor(es, off, 32);
        if (tid == 0) out[0] = mm + __logf(es) - gold[0];
    }
}

// ---------------- launch ----------------

extern "C" void kernel_launch(void* const* d_in, const int* in_sizes, int n_in,
                              void* d_out, int out_size, void* d_ws, size_t ws_size,
                              hipStream_t stream) {
    const int*   ids     = (const int*)d_in[0];
    const int*   target  = (const int*)d_in[2];
    const float* emb     = (const float*)d_in[3];
    const float* w_ih_f  = (const float*)d_in[4];
    const float* w_hh_f  = (const float*)d_in[5];
    const float* b_f     = (const float*)d_in[6];
    const float* w_ih_b  = (const float*)d_in[7];
    const float* w_hh_b  = (const float*)d_in[8];
    const float* b_b     = (const float*)d_in[9];
    const float* w_lin   = (const float*)d_in[10];
    const float* b_lin   = (const float*)d_in[11];
    const float* trans   = (const float*)d_in[12];
    const float* h0      = (const float*)d_in[13];
    const float* c0      = (const float*)d_in[14];
    float* out = (float*)d_out;

    char* ws = (char*)d_ws;
    size_t off = 0;
    float* xbuf   = (float*)(ws + off); off += (size_t)T_LEN * 256 * 4;       // 2 MB
    float* xprojP = (float*)(ws + off); off += (size_t)2 * T_LEN * G4 * 4;    // 16 MB
    float* hs     = (float*)(ws + off); off += (size_t)T_LEN * 512 * 4;       // 4 MB
    float* logits = (float*)(ws + off); off += (size_t)T_LEN * NLBL * 4;      // 256 KB
    float* srowP  = (float*)(ws + off); off += (size_t)2 * G4 * 4;            // 8 KB
    float* sh0v   = (float*)(ws + off); off += 16;
    float* gold   = (float*)(ws + off); off += 16;
    int*   hq0    = (int*)(ws + off);   off += (size_t)2 * 64 * 4;
    signed char* wq = (signed char*)(ws + off); off += (size_t)2 * G4 * H2;   // 512 KB
    float* mats1 = xbuf;                 // alias xbuf (dead after gemm_xproj)
    float* mats2 = xbuf + 256 * 1024;

    gather_k<<<T_LEN, 256, 0, stream>>>(ids, emb, xbuf);
    quant_w_k<<<512, 256, 0, stream>>>(w_hh_f, w_hh_b, wq, srowP);
    quant_h0_k<<<2, 64, 0, stream>>>(h0, hq0, sh0v);
    gemm_xproj_k<<<dim3(32, 32), 256, 0, stream>>>(xbuf, w_ih_f, w_ih_b, b_f, b_b, xprojP);
    lstm_rec_k<<<2, 512, 0, stream>>>(wq, srowP, xprojP, hq0, sh0v, c0, hs);
    logits_k<<<dim3(256, 2), 128, 0, stream>>>(hs, w_lin, b_lin, logits);
    gold_k<<<1, 256, 0, stream>>>(trans, target, logits, gold);
    crf_chain0_k<<<256, 1024, 0, stream>>>(logits, trans, mats1);
    crf_chainN_k<<<16, 1024, 0, stream>>>(mats1, mats2, 16);
    crf_finish_k<<<1, 1024, 0, stream>>>(mats2, trans, gold, out, 16);
}